// Round 1
// baseline (279.554 us; speedup 1.0000x reference)
//
#include <hip/hip_runtime.h>

// Masked smooth-L1 sum:
//   d = |out - target|; sl1 = d<1 ? 0.5 d^2 : d-0.5; sum over target!=0
// Memory-bound streaming reduction: 268 MB read -> 1 scalar.

__global__ void zero_out_kernel(float* out) {
    out[0] = 0.0f;
}

__device__ __forceinline__ float sl1_masked(float o, float t) {
    float d = fabsf(o - t);
    float s = (d < 1.0f) ? (0.5f * d * d) : (d - 0.5f);
    return (t != 0.0f) ? s : 0.0f;
}

__global__ __launch_bounds__(256) void sl1_reduce_kernel(
    const float4* __restrict__ o4,
    const float4* __restrict__ t4,
    float* __restrict__ result,
    long long n4)
{
    long long i = (long long)blockIdx.x * blockDim.x + threadIdx.x;
    const long long stride = (long long)gridDim.x * blockDim.x;
    float acc = 0.0f;
    for (; i < n4; i += stride) {
        float4 o = o4[i];
        float4 t = t4[i];
        acc += sl1_masked(o.x, t.x);
        acc += sl1_masked(o.y, t.y);
        acc += sl1_masked(o.z, t.z);
        acc += sl1_masked(o.w, t.w);
    }

    // wave-64 shuffle reduction
    #pragma unroll
    for (int off = 32; off > 0; off >>= 1)
        acc += __shfl_down(acc, off, 64);

    __shared__ float wave_sums[4];  // 256 threads = 4 waves
    const int lane = threadIdx.x & 63;
    const int wave = threadIdx.x >> 6;
    if (lane == 0) wave_sums[wave] = acc;
    __syncthreads();

    if (threadIdx.x == 0) {
        float s = wave_sums[0] + wave_sums[1] + wave_sums[2] + wave_sums[3];
        atomicAdd(result, s);  // device-scope by default on CDNA
    }
}

extern "C" void kernel_launch(void* const* d_in, const int* in_sizes, int n_in,
                              void* d_out, int out_size, void* d_ws, size_t ws_size,
                              hipStream_t stream) {
    const float* out_p    = (const float*)d_in[0];
    const float* target_p = (const float*)d_in[1];
    float* res = (float*)d_out;

    const long long n = (long long)in_sizes[0];   // 2^25, divisible by 4
    const long long n4 = n / 4;

    // d_out is poisoned to 0xAA before every timed launch — zero it first.
    zero_out_kernel<<<1, 1, 0, stream>>>(res);

    const int block = 256;
    const int grid = 2048;  // 8 blocks/CU worth of waves; 16 float4/thread
    sl1_reduce_kernel<<<grid, block, 0, stream>>>(
        (const float4*)out_p, (const float4*)target_p, res, n4);
}